// Round 10
// baseline (1059.496 us; speedup 1.0000x reference)
//
#include <hip/hip_runtime.h>

#define S_ROWS 16384
#define T_ROWS 32768
#define NROWS  49152
#define DDIM   4096
#define C      21
#define KSPLIT 2
#define RPB    384                     // rows per block (64 lanes x 6 rows/lane)

// workspace layout (in floats)
#define WT_OFF 0
#define WT_SZ  (C * DDIM)              // 86016: W transposed to [C][D]
#define P_OFF  (WT_OFF + WT_SZ)
#define P_SLOT (NROWS * C)             // 1032192 per k-slot
#define DM_OFF (P_OFF + KSPLIT * P_SLOT)
#define N_OFF  (DM_OFF + C)
#define NW_OFF (N_OFF + C)

// LDS layout for k_gemm (floats): double-buffered X + W tiles
// X tile: 384 rows x 32 k = 12288 floats; W tile: 24 x 32 = 768 floats
#define XB0 0
#define XB1 12288
#define WB0 24576
#define WB1 (24576 + 768)
#define SMEM_FL 26112                  // 104448 B; reduction reuses [0..10752)

// ---------------- kernel 1: transpose W, zero accumulators ----------------
__global__ void k_prep(const float* __restrict__ W, float* __restrict__ ws) {
    int idx = blockIdx.x * 256 + threadIdx.x;
    if (idx < C * DDIM) {
        int c = idx / DDIM, d = idx - c * DDIM;
        ws[WT_OFF + idx] = W[d * C + c];
    }
    if (blockIdx.x == 0 && threadIdx.x < 2 * C) {
        ws[DM_OFF + threadIdx.x] = 0.0f;   // zeroes delta_margin[21] + num[21]
    }
}

// async 16B global->LDS DMA (zero VGPR round-trip; lds dest = wave base + lane*16)
typedef const __attribute__((address_space(1))) void* gas_ptr;
typedef __attribute__((address_space(3))) void* las_ptr;
__device__ __forceinline__ void gload_lds16(const float* g, float* l) {
    __builtin_amdgcn_global_load_lds((gas_ptr)g, (las_ptr)l, 16, 0, 0);
}

// ---------------- kernel 2: tiled GEMM partials -------------------------
// block: 512 threads = 8 waves; 384 rows/block; grid (128 row-groups, 2 k-chunks)
// = 256 blocks = EXACTLY 1 block/CU, 8 waves/CU = 2 waves/SIMD.
// wave w owns the 4-wide k-slice (float4 slot w) of each 32-wide k-tile;
// lane l owns rows l + r*64, r=0..5. acc[6][21] in registers; W from LDS.
//
// HISTORY / DISCIPLINE:
//  - R0/R1: acc spilled when peak pressure > launch_bounds cap. Keep margin wide.
//  - R3: reg-staged prefetch re-spilled. Prefetch must cost 0 VGPR (DMA only).
//  - R4->R5: global_load_lds dbuf; 3 blocks/CU exact -> 232us total (k_gemm
//    ~190us, LDS-throughput-bound: 42 broadcast W b128 reads per wave-iter).
//  - R6: counted-vmcnt NULL (latency already covered at 3 blocks/CU).
//  - R7: W via wave-uniform global loads REGRESSED (L2 latency chains).
//  - R8: RPB=384 with per-BLOCK src/tgt select CRASHED (384 !| 16384; OOB).
//  - R9: RPB=384, 4 waves, per-8-row-group select: correct, no spill, W
//    amortized -- but 1 wave/SIMD (Occ 11.6%) exposed every ds_read/VALU
//    latency; 5.6us/iter vs 1.1us model -> 363us. Per-CU models need >=2
//    waves/SIMD for latency hiding.
//  - R10 (this): same 384-row tile + W amortization, but 512 threads =
//    8 waves, each wave a 4-wide k-slice: per-wave serial chain halves
//    (6 X + 21 W reads, 504 FMA), 2 waves/SIMD cover LDS latency.
//    Per-CU-iter: LDS 216 reads (1.08us) / VALU 2016cyc/SIMD (0.84us) /
//    HBM 51KB (2.07us) -> HBM-bound ~140us. DMA t+1 issues immediately
//    after the iter-(t-1) barrier -> HBM streams through compute+drain.
//  - XOR swizzle (rule 21 both-sides): physical float4 slot =
//    logical ^ (row&7). DMA pre-swizzles the per-lane GLOBAL address (group
//    rows are 8-aligned so (grow+r8)&7 == r8; same 128B segment per 8-lane
//    group -> coalescing intact); compute read applies the same XOR.
//  - src/tgt selected PER 8-ROW DMA GROUP (R8 lesson): every op's 8-row
//    range is 8-aligned; 16384 boundary is 8-aligned -> no op straddles.
__launch_bounds__(512, 1)
__global__ void k_gemm(const float* __restrict__ src, const float* __restrict__ tgt,
                       float* __restrict__ ws) {
    __shared__ float smem[SMEM_FL];
    const int tid = threadIdx.x;
    const int g   = blockIdx.x;             // row group (384 rows)
    const int ks  = blockIdx.y;             // k chunk (2048 d)
    const int l   = tid & 63, w = tid >> 6; // 8 waves
    const int rg0 = g * RPB;
    const float* wt = ws + WT_OFF;

    // per-lane pre-swizzled global source pointers for the 6 X DMA calls
    // (wave w stages rows [w*48, w*48+48), 8 rows per op)
    const int r8 = l >> 3, c8 = l & 7;
    const int fsw_src = (c8 ^ r8) << 2;     // swizzled float4 -> float offset
    const float* xg[6];
#pragma unroll
    for (int i = 0; i < 6; ++i) {
        const int grow = rg0 + w * 48 + i * 8;          // 8-row group start
        const float* bp = (grow < S_ROWS)
            ? (src + (size_t)grow * DDIM)
            : (tgt + (size_t)(grow - S_ROWS) * DDIM);
        xg[i] = bp + (size_t)r8 * DDIM + ks * 2048 + fsw_src;
    }
    // W DMA: waves 0..2 each cover 8 rows (rows 21..23 read harmless ws bytes)
    const float* wg = wt + (size_t)(w * 8 + r8) * DDIM + ks * 2048 + (c8 << 2);

    float acc[6][C];
#pragma unroll
    for (int r = 0; r < 6; ++r)
#pragma unroll
        for (int c = 0; c < C; ++c) acc[r][c] = 0.0f;

    // prologue: stage tile 0 into buffer 0
#pragma unroll
    for (int i = 0; i < 6; ++i)
        gload_lds16(xg[i], &smem[XB0 + (w * 48 + i * 8) * 32]);
    if (w < 3) gload_lds16(wg, &smem[WB0 + w * 256]);
    __syncthreads();

#pragma unroll 1
    for (int t = 0; t < 64; ++t) {
        const int xcur = (t & 1) ? XB1 : XB0;
        const int wcur = (t & 1) ? WB1 : WB0;
        // issue DMA for tile t+1 into the other buffer (flies under compute
        // AND under the end-of-iter drain -> HBM streams continuously)
        if (t < 63) {
            const int xnxt = (t & 1) ? XB0 : XB1;
            const int wnxt = (t & 1) ? WB0 : WB1;
            const int koff = (t + 1) * 32;
#pragma unroll
            for (int i = 0; i < 6; ++i)
                gload_lds16(xg[i] + koff, &smem[xnxt + (w * 48 + i * 8) * 32]);
            if (w < 3) gload_lds16(wg + koff, &smem[wnxt + w * 256]);
        }

        // single 4-wide pass: this wave's float4 slot is w
        float4 xr[6];
#pragma unroll
        for (int r = 0; r < 6; ++r) {
            const int row = l + r * 64;
            xr[r] = *(const float4*)
                &smem[xcur + row * 32 + ((w ^ (row & 7)) << 2)];
        }
#pragma unroll
        for (int c = 0; c < C; ++c) {
            float4 wv = *(const float4*)&smem[wcur + c * 32 + w * 4];
#pragma unroll
            for (int r = 0; r < 6; ++r) {
                acc[r][c] += xr[r].x * wv.x + xr[r].y * wv.y +
                             xr[r].z * wv.z + xr[r].w * wv.w;
            }
        }
        __syncthreads();   // drains DMA vmcnt + lgkm; one barrier per iter
    }

    // cross-wave reduction: six sub-phases of 64 rows; sum over 8 waves
    // (8 x 1344 = 10752 fl of LDS per phase); acc statically indexed (rule #20)
    float* pout = ws + P_OFF + (size_t)ks * P_SLOT;
#pragma unroll
    for (int h = 0; h < 6; ++h) {
#pragma unroll
        for (int c = 0; c < C; ++c)
            smem[w * 1344 + l * 21 + c] = acc[h][c];
        __syncthreads();
        for (int idx = tid; idx < 1344; idx += 512) {
            int row = idx / 21, c = idx - row * 21;
            float s = 0.0f;
#pragma unroll
            for (int ww = 0; ww < 8; ++ww) s += smem[ww * 1344 + row * 21 + c];
            pout[(size_t)(rg0 + h * 64 + row) * 21 + c] = s;
        }
        __syncthreads();
    }
}

// ---------------- kernel 3: sum partials, softmax, stats ----------------
__global__ void k_phaseB(const float* __restrict__ b_cls, float* __restrict__ ws,
                         float* __restrict__ out) {
    const int tid = threadIdx.x;
    const int row = blockIdx.x * 256 + tid;
    const float* P = ws + P_OFF;
    float lg[C];
#pragma unroll
    for (int c = 0; c < C; ++c) lg[c] = b_cls[c];
    for (int k = 0; k < KSPLIT; ++k) {
        const float* p = P + (size_t)k * P_SLOT + (size_t)row * C;
#pragma unroll
        for (int c = 0; c < C; ++c) lg[c] += p[c];
    }
    float m = lg[0];
#pragma unroll
    for (int c = 1; c < C; ++c) m = fmaxf(m, lg[c]);
    float e[C], s = 0.0f;
#pragma unroll
    for (int c = 0; c < C; ++c) { e[c] = __expf(lg[c] - m); s += e[c]; }
    float inv = 1.0f / s;

    if (row < S_ROWS) {                    // block-uniform branch (64 src blocks)
        float* o = out + (size_t)row * 22;
#pragma unroll
        for (int c = 0; c < C; ++c) o[c] = e[c] * inv;
    } else {
        __shared__ float s_dm[C], s_n[C];
        if (tid < C) { s_dm[tid] = 0.0f; s_n[tid] = 0.0f; }
        __syncthreads();
        float top = -1.0f, sum = 0.0f; int arg = 0;
#pragma unroll
        for (int c = 0; c < C; ++c) {
            float p = e[c] * inv; sum += p;
            if (p > top) { top = p; arg = c; }   // strict > keeps first argmax
        }
        float margin = top - (sum - top) * (1.0f / (C - 1));
        if (arg != 0) {
            atomicAdd(&s_dm[arg], margin);
            atomicAdd(&s_n[arg], 1.0f);
        }
        __syncthreads();
        if (tid < C) {
            atomicAdd(&ws[DM_OFF + tid], s_dm[tid]);
            atomicAdd(&ws[N_OFF + tid], s_n[tid]);
        }
    }
}

// ---------------- kernel 4: blend + minmax normalize (1 block) ----------
__global__ void k_final(const float* __restrict__ tmf, const float* __restrict__ rec,
                        float* __restrict__ ws) {
    __shared__ float wv[C];
    __shared__ float mm[2];
    const int t = threadIdx.x;
    if (t < C) {
        float r = rec[0];
        float n = ws[N_OFF + t];
        float blended = (tmf[t] * r + ws[DM_OFF + t] / (n + 1e-6f)) / (r + 1.0f);
        float sn = 0.0f;
        for (int c = 0; c < C; ++c) sn += ws[N_OFF + c];
        wv[t] = (sn > 0.0f) ? blended : tmf[t];
    }
    __syncthreads();
    if (t == 0) {
        float mn = wv[0], mx = wv[0];
        for (int c = 1; c < C; ++c) { mn = fminf(mn, wv[c]); mx = fmaxf(mx, wv[c]); }
        mm[0] = mn; mm[1] = mx;
    }
    __syncthreads();
    if (t < C) ws[NW_OFF + t] = (wv[t] - mm[0]) / (mm[1] - mm[0] + 1e-12f);
}

// ---------------- kernel 5: gather weight column ------------------------
__global__ void k_gather(const int* __restrict__ label, const float* __restrict__ ws,
                         float* __restrict__ out) {
    int s = blockIdx.x * 256 + threadIdx.x;
    out[(size_t)s * 22 + 21] = ws[NW_OFF + label[s]];
}

extern "C" void kernel_launch(void* const* d_in, const int* in_sizes, int n_in,
                              void* d_out, int out_size, void* d_ws, size_t ws_size,
                              hipStream_t stream) {
    const float* src   = (const float*)d_in[0];
    const float* tgt   = (const float*)d_in[1];
    const float* W     = (const float*)d_in[2];
    const float* b     = (const float*)d_in[3];
    const int*   label = (const int*)d_in[4];
    const float* tmf   = (const float*)d_in[5];
    const float* rec   = (const float*)d_in[6];
    float* out = (float*)d_out;
    float* ws  = (float*)d_ws;

    k_prep<<<(C * DDIM + 255) / 256, 256, 0, stream>>>(W, ws);
    k_gemm<<<dim3(NROWS / RPB, KSPLIT), 512, 0, stream>>>(src, tgt, ws);
    k_phaseB<<<NROWS / 256, 256, 0, stream>>>(b, ws, out);
    k_final<<<1, 64, 0, stream>>>(tmf, rec, ws);
    k_gather<<<S_ROWS / 256, 256, 0, stream>>>(label, ws, out);
}

// Round 11
// 285.305 us; speedup vs baseline: 3.7136x; 3.7136x over previous
//
#include <hip/hip_runtime.h>

#define S_ROWS 16384
#define T_ROWS 32768
#define NROWS  49152
#define DDIM   4096
#define C      21
#define KSPLIT 4
#define RPB    256                     // rows per block (64 lanes x 4 rows/lane)

// workspace layout (in floats)
#define WT_OFF 0
#define WT_SZ  (C * DDIM)              // 86016: W transposed to [C][D]
#define P_OFF  (WT_OFF + WT_SZ)
#define P_SLOT (NROWS * C)             // 1032192 per k-slot
#define DM_OFF (P_OFF + KSPLIT * P_SLOT)
#define N_OFF  (DM_OFF + C)
#define NW_OFF (N_OFF + C)

// LDS layout for k_gemm (floats): double-buffered X + W tiles
// X tile: 256 rows x 32 k = 8192 floats; W tile: 24 x 32 = 768 floats
#define XB0 0
#define XB1 8192
#define WB0 16384
#define WB1 (16384 + 768)
#define SMEM_FL 17920                  // 71680 B; reduction reuses [0..10752)

// ---------------- kernel 1: transpose W, zero accumulators ----------------
__global__ void k_prep(const float* __restrict__ W, float* __restrict__ ws) {
    int idx = blockIdx.x * 256 + threadIdx.x;
    if (idx < C * DDIM) {
        int c = idx / DDIM, d = idx - c * DDIM;
        ws[WT_OFF + idx] = W[d * C + c];
    }
    if (blockIdx.x == 0 && threadIdx.x < 2 * C) {
        ws[DM_OFF + threadIdx.x] = 0.0f;   // zeroes delta_margin[21] + num[21]
    }
}

// async 16B global->LDS DMA (zero VGPR round-trip; lds dest = wave base + lane*16)
typedef const __attribute__((address_space(1))) void* gas_ptr;
typedef __attribute__((address_space(3))) void* las_ptr;
__device__ __forceinline__ void gload_lds16(const float* g, float* l) {
    __builtin_amdgcn_global_load_lds((gas_ptr)g, (las_ptr)l, 16, 0, 0);
}

// ---------------- kernel 2: tiled GEMM partials -------------------------
// block: 256 threads = 4 waves; 256 rows/block; grid (192 row-groups, 4 k-chunks)
// = 768 blocks at 2 blocks/CU (1.5 rounds, finish-stagger balances).
// wave w covers d-subrange [w*8, w*8+8) of each 32-wide k-tile; lane l owns
// rows l + r*64, r=0..3. acc[4][21] in registers; W broadcast from LDS.
//
// HISTORY / DISCIPLINE (10 rounds of evidence):
//  - R0/R1/R3/R10: acc spills whenever peak pressure exceeds the launch_bounds
//    cap. acc[4][21]=84 at (256,2) is the PROVEN no-spill point (R2/R4:
//    VGPR=128, clean). R=6 rows/lane failed 3 ways (R8 OOB, R9 1-wave/SIMD
//    latency, R10 spill at 512thr) -- abandoned.
//  - R5 (R=2, 3 blocks/CU): 190us, LDS-READ-BOUND (552 b128 x 12cyc/CU-iter
//    matches measured 1.0us/iter). R6 counted-vmcnt there: NULL (pipe not
//    binding). R7 W-via-global: regressed (L2 latency chains).
//  - R4 (THIS geometry, depth-1 __syncthreads): 370us = 3.85us/iter vs
//    resource model 1.4 (HBM 1.37 / LDS 1.0 / VALU 0.67): BURSTY -- with 2
//    barrier-synced streams/CU, issue->compute->full-drain leaves HBM idle.
//  - R11 (this): R4 geometry + R6's counted-vmcnt depth-2 pipeline (both
//    individually verified): prologue stages tiles 0,1; iter t waits
//    vmcnt(ops of tile t+1) = 9 (waves 0-2, which also DMA W) or 8 (wave 3),
//    raw s_barrier, compute, raw s_barrier (WAR), issue tile t+2. Never
//    vmcnt(0) in-loop -> 2 tiles x 2 blocks = 4 DMA streams/CU continuously
//    in flight. W amortized over 4 rows/lane: LDS 50 reads/wave-iter vs
//    R5's 46 per HALF the rows.
//  - XOR swizzle (rule 21 both-sides): physical float4 slot =
//    logical ^ (row&7); DMA pre-swizzles the per-lane GLOBAL address (8-row
//    groups are 8-aligned; same 128B segment per 8-lane group -> coalescing
//    intact); compute read applies the same XOR -> conflict-free.
//  - src/tgt selected PER 8-ROW DMA GROUP (R8 lesson): 8-aligned ranges
//    cannot straddle the 16384 boundary.
__launch_bounds__(256, 2)
__global__ void k_gemm(const float* __restrict__ src, const float* __restrict__ tgt,
                       float* __restrict__ ws) {
    __shared__ float smem[SMEM_FL];
    const int tid = threadIdx.x;
    const int g   = blockIdx.x;             // row group (256 rows)
    const int ks  = blockIdx.y;             // k chunk (1024 d)
    const int l   = tid & 63, w = tid >> 6;
    const int w8  = w * 8;
    const int rg0 = g * RPB;
    const float* wt = ws + WT_OFF;

    // per-lane pre-swizzled global source pointers for the 8 X DMA calls
    // (wave w stages rows [w*64, w*64+64), 8 rows per op)
    const int r8 = l >> 3, c8 = l & 7;
    const int fsw_src = (c8 ^ r8) << 2;     // swizzled float4 -> float offset
    const float* xg[8];
#pragma unroll
    for (int i = 0; i < 8; ++i) {
        const int grow = rg0 + w * 64 + i * 8;          // 8-row group start
        const float* bp = (grow < S_ROWS)
            ? (src + (size_t)grow * DDIM)
            : (tgt + (size_t)(grow - S_ROWS) * DDIM);
        xg[i] = bp + (size_t)r8 * DDIM + ks * 1024 + fsw_src;
    }
    // W DMA: waves 0..2 each cover 8 rows (rows 21..23 read harmless ws bytes)
    const float* wg = wt + (size_t)(w * 8 + r8) * DDIM + ks * 1024 + (c8 << 2);

    float acc[4][C];
#pragma unroll
    for (int r = 0; r < 4; ++r)
#pragma unroll
        for (int c = 0; c < C; ++c) acc[r][c] = 0.0f;

    // prologue: stage tile 0 -> buf0, tile 1 -> buf1 (2 tiles in flight)
#pragma unroll
    for (int i = 0; i < 8; ++i)
        gload_lds16(xg[i], &smem[XB0 + (w * 64 + i * 8) * 32]);
    if (w < 3) gload_lds16(wg, &smem[WB0 + w * 256]);
#pragma unroll
    for (int i = 0; i < 8; ++i)
        gload_lds16(xg[i] + 32, &smem[XB1 + (w * 64 + i * 8) * 32]);
    if (w < 3) gload_lds16(wg + 32, &smem[WB1 + w * 256]);

#pragma unroll 1
    for (int t = 0; t < 32; ++t) {
        const int xcur = (t & 1) ? XB1 : XB0;
        const int wcur = (t & 1) ? WB1 : WB0;

        // wait for tile t only: newer outstanding = tile t+1's ops (9 or 8)
        if (t < 31) {
            if (w < 3) asm volatile("s_waitcnt vmcnt(9)" ::: "memory");
            else       asm volatile("s_waitcnt vmcnt(8)" ::: "memory");
        } else {
            asm volatile("s_waitcnt vmcnt(0)" ::: "memory");
        }
        asm volatile("s_barrier" ::: "memory");   // tile t visible to all waves

        // two sequential 4-wide passes over this wave's 8-wide d-slice
#pragma unroll 1
        for (int dd = 0; dd < 8; dd += 4) {
            const int f4 = w * 2 + (dd >> 2);   // logical float4 slot
            float4 xr[4];
#pragma unroll
            for (int r = 0; r < 4; ++r) {
                const int row = l + r * 64;
                xr[r] = *(const float4*)
                    &smem[xcur + row * 32 + ((f4 ^ (row & 7)) << 2)];
            }
#pragma unroll
            for (int c = 0; c < C; ++c) {
                float4 wv = *(const float4*)&smem[wcur + c * 32 + w8 + dd];
#pragma unroll
                for (int r = 0; r < 4; ++r) {
                    acc[r][c] += xr[r].x * wv.x + xr[r].y * wv.y +
                                 xr[r].z * wv.z + xr[r].w * wv.w;
                }
            }
        }

        asm volatile("s_barrier" ::: "memory");   // WAR: all reads of buf done
        if (t < 30) {                             // issue tile t+2 into freed buf
            const int koff = (t + 2) * 32;
#pragma unroll
            for (int i = 0; i < 8; ++i)
                gload_lds16(xg[i] + koff, &smem[xcur + (w * 64 + i * 8) * 32]);
            if (w < 3) gload_lds16(wg + koff, &smem[wcur + w * 256]);
        }
    }

    // cross-wave reduction (two halves of 128 rows, 10752 fl), store partials;
    // h statically unrolled so acc stays register-indexed (rule #20)
    float* pout = ws + P_OFF + (size_t)ks * P_SLOT;
#pragma unroll
    for (int h = 0; h < 2; ++h) {
#pragma unroll
        for (int c = 0; c < C; ++c) {
            smem[w * 2688 + l * 21 + c]        = acc[2 * h][c];
            smem[w * 2688 + (l + 64) * 21 + c] = acc[2 * h + 1][c];
        }
        __syncthreads();
        for (int idx = tid; idx < 2688; idx += 256) {
            int row = idx / 21, c = idx - row * 21;
            float s = smem[row * 21 + c] + smem[2688 + row * 21 + c] +
                      smem[5376 + row * 21 + c] + smem[8064 + row * 21 + c];
            pout[(size_t)(rg0 + h * 128 + row) * 21 + c] = s;
        }
        __syncthreads();
    }
}

// ---------------- kernel 3: sum partials, softmax, stats ----------------
__global__ void k_phaseB(const float* __restrict__ b_cls, float* __restrict__ ws,
                         float* __restrict__ out) {
    const int tid = threadIdx.x;
    const int row = blockIdx.x * 256 + tid;
    const float* P = ws + P_OFF;
    float lg[C];
#pragma unroll
    for (int c = 0; c < C; ++c) lg[c] = b_cls[c];
    for (int k = 0; k < KSPLIT; ++k) {
        const float* p = P + (size_t)k * P_SLOT + (size_t)row * C;
#pragma unroll
        for (int c = 0; c < C; ++c) lg[c] += p[c];
    }
    float m = lg[0];
#pragma unroll
    for (int c = 1; c < C; ++c) m = fmaxf(m, lg[c]);
    float e[C], s = 0.0f;
#pragma unroll
    for (int c = 0; c < C; ++c) { e[c] = __expf(lg[c] - m); s += e[c]; }
    float inv = 1.0f / s;

    if (row < S_ROWS) {                    // block-uniform branch (64 src blocks)
        float* o = out + (size_t)row * 22;
#pragma unroll
        for (int c = 0; c < C; ++c) o[c] = e[c] * inv;
    } else {
        __shared__ float s_dm[C], s_n[C];
        if (tid < C) { s_dm[tid] = 0.0f; s_n[tid] = 0.0f; }
        __syncthreads();
        float top = -1.0f, sum = 0.0f; int arg = 0;
#pragma unroll
        for (int c = 0; c < C; ++c) {
            float p = e[c] * inv; sum += p;
            if (p > top) { top = p; arg = c; }   // strict > keeps first argmax
        }
        float margin = top - (sum - top) * (1.0f / (C - 1));
        if (arg != 0) {
            atomicAdd(&s_dm[arg], margin);
            atomicAdd(&s_n[arg], 1.0f);
        }
        __syncthreads();
        if (tid < C) {
            atomicAdd(&ws[DM_OFF + tid], s_dm[tid]);
            atomicAdd(&ws[N_OFF + tid], s_n[tid]);
        }
    }
}

// ---------------- kernel 4: blend + minmax normalize (1 block) ----------
__global__ void k_final(const float* __restrict__ tmf, const float* __restrict__ rec,
                        float* __restrict__ ws) {
    __shared__ float wv[C];
    __shared__ float mm[2];
    const int t = threadIdx.x;
    if (t < C) {
        float r = rec[0];
        float n = ws[N_OFF + t];
        float blended = (tmf[t] * r + ws[DM_OFF + t] / (n + 1e-6f)) / (r + 1.0f);
        float sn = 0.0f;
        for (int c = 0; c < C; ++c) sn += ws[N_OFF + c];
        wv[t] = (sn > 0.0f) ? blended : tmf[t];
    }
    __syncthreads();
    if (t == 0) {
        float mn = wv[0], mx = wv[0];
        for (int c = 1; c < C; ++c) { mn = fminf(mn, wv[c]); mx = fmaxf(mx, wv[c]); }
        mm[0] = mn; mm[1] = mx;
    }
    __syncthreads();
    if (t < C) ws[NW_OFF + t] = (wv[t] - mm[0]) / (mm[1] - mm[0] + 1e-12f);
}

// ---------------- kernel 5: gather weight column ------------------------
__global__ void k_gather(const int* __restrict__ label, const float* __restrict__ ws,
                         float* __restrict__ out) {
    int s = blockIdx.x * 256 + threadIdx.x;
    out[(size_t)s * 22 + 21] = ws[NW_OFF + label[s]];
}

extern "C" void kernel_launch(void* const* d_in, const int* in_sizes, int n_in,
                              void* d_out, int out_size, void* d_ws, size_t ws_size,
                              hipStream_t stream) {
    const float* src   = (const float*)d_in[0];
    const float* tgt   = (const float*)d_in[1];
    const float* W     = (const float*)d_in[2];
    const float* b     = (const float*)d_in[3];
    const int*   label = (const int*)d_in[4];
    const float* tmf   = (const float*)d_in[5];
    const float* rec   = (const float*)d_in[6];
    float* out = (float*)d_out;
    float* ws  = (float*)d_ws;

    k_prep<<<(C * DDIM + 255) / 256, 256, 0, stream>>>(W, ws);
    k_gemm<<<dim3(NROWS / RPB, KSPLIT), 256, 0, stream>>>(src, tgt, ws);
    k_phaseB<<<NROWS / 256, 256, 0, stream>>>(b, ws, out);
    k_final<<<1, 64, 0, stream>>>(tmf, rec, ws);
    k_gather<<<S_ROWS / 256, 256, 0, stream>>>(label, ws, out);
}